// Round 4
// baseline (1427.041 us; speedup 1.0000x reference)
//
#include <hip/hip_runtime.h>
#include <hip/hip_fp16.h>

#define DEVI __device__ __forceinline__

typedef __attribute__((ext_vector_type(4))) float f32x4;
typedef __attribute__((ext_vector_type(8))) short bf16x8;
typedef __attribute__((ext_vector_type(8))) _Float16 f16x8;
typedef __attribute__((ext_vector_type(2))) _Float16 f16x2;
typedef unsigned long long ull;

DEVI ushort f2bf(float x) {
  union { float f; unsigned u; } v; v.f = x;
  unsigned r = v.u + 0x7fffu + ((v.u >> 16) & 1u);
  return (ushort)(r >> 16);
}
DEVI float bf2f(ushort b) {
  union { unsigned u; float f; } v; v.u = ((unsigned)b) << 16; return v.f;
}
DEVI unsigned packh2(float a, float b) {
  return ((unsigned)__half_as_ushort(__float2half(b)) << 16) |
         (unsigned)__half_as_ushort(__float2half(a));
}
DEVI float dot2(unsigned a, unsigned b, float c) {
#if __has_builtin(__builtin_amdgcn_fdot2)
  return __builtin_amdgcn_fdot2(__builtin_bit_cast(f16x2, a),
                                __builtin_bit_cast(f16x2, b), c, false);
#else
  f16x2 ha = __builtin_bit_cast(f16x2, a), hb = __builtin_bit_cast(f16x2, b);
  return c + (float)ha[0] * (float)hb[0] + (float)ha[1] * (float)hb[1];
#endif
}
DEVI float sigmoidf_(float x) { return 1.f / (1.f + __expf(-x)); }
// NaN-free fast tanh: e=exp(2x); 1-2/(e+1). e=inf -> 1, e=0 -> -1.
DEVI float tanh_fast(float x) {
  float e = __expf(2.f * x);
  return 1.f - 2.f / (e + 1.f);
}

// relaxed agent-scope (L3 coherence point) 64-bit tagged-word accesses
DEVI void gstore64(ull* p, ull v) {
  __hip_atomic_store(p, v, __ATOMIC_RELAXED, __HIP_MEMORY_SCOPE_AGENT);
}
DEVI ull gload64(const ull* p) {
  return __hip_atomic_load(p, __ATOMIC_RELAXED, __HIP_MEMORY_SCOPE_AGENT);
}

// ---------------------------------------------------------------------------
// Generic 128x128-tile bf16 MFMA GEMM:  C[M,N] = A[M,K] @ Bw[N,K]^T + bias
// SPLIT=true: hi/lo split-bf16, 3 MFMA passes (~fp32 accuracy).
// ABF16/BBF16: operand already bf16 (ushort) in gmem.
// SWZ: XCD-affinity block swizzle for the 16x250 out-GEMM grid (launch 4096
// 1-D blocks; all 16 M-blocks of one N-slice get bid == y (mod 8) -> same XCD
// L2 caches the B slice once). Pure perf heuristic: any mapping is correct.
// ---------------------------------------------------------------------------
template<bool SPLIT, bool ABF16, bool BBF16, bool SWZ>
__global__ __launch_bounds__(256)
void gemm_kernel(const void* __restrict__ A_, int lda, const int* __restrict__ Aidx,
                 const void* __restrict__ Bw_, int ldb,
                 const float* __restrict__ bias, float* __restrict__ C,
                 int N, int K)
{
  constexpr int BK  = SPLIT ? 32 : 64;
  constexpr int LDT = BK + 8;
  constexpr int NV  = (128 * BK / 4) / 256;

  __shared__ ushort Ah[128 * LDT];
  __shared__ ushort Bh[128 * LDT];
  __shared__ ushort Al[SPLIT ? 128 * LDT : 4];
  __shared__ ushort Bl[SPLIT ? 128 * LDT : 4];

  int bm, bn;
  if (SWZ) {
    int bid = blockIdx.x;
    int r8 = bid & 7, k = bid >> 3;
    int x = k & 15, yhi = k >> 4;
    int y = yhi * 8 + r8;
    if (y >= 250) return;
    bm = x * 128; bn = y * 128;
  } else {
    bm = blockIdx.x * 128; bn = blockIdx.y * 128;
  }

  const int tid  = threadIdx.x;
  const int lane = tid & 63, wave = tid >> 6;
  const int wr   = wave >> 1, wc = wave & 1;
  const int fr   = lane & 15, quad = lane >> 4;

  f32x4 acc[4][4] = {};

  for (int kt = 0; kt < K; kt += BK) {
    __syncthreads();
#pragma unroll
    for (int i = 0; i < NV; ++i) {
      int v   = i * 256 + tid;
      int row = v / (BK / 4);
      int c4  = (v % (BK / 4)) * 4;
      int arow = Aidx ? Aidx[bm + row] : (bm + row);
      if (ABF16) {
        const ushort* A = (const ushort*)A_;
        ushort4 h = *reinterpret_cast<const ushort4*>(A + (size_t)arow * lda + kt + c4);
        *reinterpret_cast<ushort4*>(&Ah[row * LDT + c4]) = h;
      } else {
        const float* A = (const float*)A_;
        const float4 x = *reinterpret_cast<const float4*>(A + (size_t)arow * lda + kt + c4);
        ushort4 h; h.x = f2bf(x.x); h.y = f2bf(x.y); h.z = f2bf(x.z); h.w = f2bf(x.w);
        *reinterpret_cast<ushort4*>(&Ah[row * LDT + c4]) = h;
        if (SPLIT) {
          ushort4 l;
          l.x = f2bf(x.x - bf2f(h.x)); l.y = f2bf(x.y - bf2f(h.y));
          l.z = f2bf(x.z - bf2f(h.z)); l.w = f2bf(x.w - bf2f(h.w));
          *reinterpret_cast<ushort4*>(&Al[row * LDT + c4]) = l;
        }
      }
    }
#pragma unroll
    for (int i = 0; i < NV; ++i) {
      int v   = i * 256 + tid;
      int row = v / (BK / 4);
      int c4  = (v % (BK / 4)) * 4;
      if (BBF16) {
        const ushort* B16 = (const ushort*)Bw_;
        ushort4 h = *reinterpret_cast<const ushort4*>(B16 + (size_t)(bn + row) * ldb + kt + c4);
        *reinterpret_cast<ushort4*>(&Bh[row * LDT + c4]) = h;
      } else {
        const float* Bw = (const float*)Bw_;
        const float4 x = *reinterpret_cast<const float4*>(Bw + (size_t)(bn + row) * ldb + kt + c4);
        ushort4 h; h.x = f2bf(x.x); h.y = f2bf(x.y); h.z = f2bf(x.z); h.w = f2bf(x.w);
        *reinterpret_cast<ushort4*>(&Bh[row * LDT + c4]) = h;
        if (SPLIT) {
          ushort4 l;
          l.x = f2bf(x.x - bf2f(h.x)); l.y = f2bf(x.y - bf2f(h.y));
          l.z = f2bf(x.z - bf2f(h.z)); l.w = f2bf(x.w - bf2f(h.w));
          *reinterpret_cast<ushort4*>(&Bl[row * LDT + c4]) = l;
        }
      }
    }
    __syncthreads();
#pragma unroll
    for (int ks = 0; ks < BK; ks += 32) {
      bf16x8 ah[4], bh[4];
#pragma unroll
      for (int i = 0; i < 4; ++i) {
        ah[i] = *reinterpret_cast<const bf16x8*>(&Ah[(wr * 64 + i * 16 + fr) * LDT + ks + quad * 8]);
        bh[i] = *reinterpret_cast<const bf16x8*>(&Bh[(wc * 64 + i * 16 + fr) * LDT + ks + quad * 8]);
      }
      if (SPLIT) {
        bf16x8 al[4], bl[4];
#pragma unroll
        for (int i = 0; i < 4; ++i) {
          al[i] = *reinterpret_cast<const bf16x8*>(&Al[(wr * 64 + i * 16 + fr) * LDT + ks + quad * 8]);
          bl[i] = *reinterpret_cast<const bf16x8*>(&Bl[(wc * 64 + i * 16 + fr) * LDT + ks + quad * 8]);
        }
#pragma unroll
        for (int i = 0; i < 4; ++i)
#pragma unroll
          for (int j = 0; j < 4; ++j) {
            acc[i][j] = __builtin_amdgcn_mfma_f32_16x16x32_bf16(ah[i], bh[j], acc[i][j], 0, 0, 0);
            acc[i][j] = __builtin_amdgcn_mfma_f32_16x16x32_bf16(ah[i], bl[j], acc[i][j], 0, 0, 0);
            acc[i][j] = __builtin_amdgcn_mfma_f32_16x16x32_bf16(al[i], bh[j], acc[i][j], 0, 0, 0);
          }
      } else {
#pragma unroll
        for (int i = 0; i < 4; ++i)
#pragma unroll
          for (int j = 0; j < 4; ++j)
            acc[i][j] = __builtin_amdgcn_mfma_f32_16x16x32_bf16(ah[i], bh[j], acc[i][j], 0, 0, 0);
      }
    }
  }
#pragma unroll
  for (int i = 0; i < 4; ++i)
#pragma unroll
    for (int j = 0; j < 4; ++j)
#pragma unroll
      for (int r = 0; r < 4; ++r) {
        int m = bm + wr * 64 + i * 16 + quad * 4 + r;
        int n = bn + wc * 64 + j * 16 + fr;
        float vv = acc[i][j][r];
        if (bias) vv += bias[n];
        C[(size_t)m * N + n] = vv;
      }
}

// ---------------------------------------------------------------------------
// prep2: algebraic pre-fold in exact f32.
//   Bcomb rows 0:256   = Wv                      (vals = features@Wv^T + bv)
//   Bcomb rows 256+e,f = Wkq[f,e] = sum_d Wk[d,f]*Wq[d,e]
//                                               (K2 = features@Wkq + bk@Wq)
//   bias512 = [bv | bkq],  bkq[e] = sum_d bk[d]*Wq[d,e]
//   wkbq[f] = sum_d Wk[d,f]*bq[d],  cbb = bk.bq  (sb = features.wkbq + cbb)
//   bsum = b_ih + b_hh
// ---------------------------------------------------------------------------
__global__ __launch_bounds__(256)
void prep2_kernel(const float* __restrict__ Wk, const float* __restrict__ Wq,
                  const float* __restrict__ Wv, const float* __restrict__ bk,
                  const float* __restrict__ bq, const float* __restrict__ b_ih,
                  const float* __restrict__ b_hh, const float* __restrict__ bv,
                  float* __restrict__ Bcomb, float* __restrict__ bias512,
                  float* __restrict__ bsum, float* __restrict__ wkbq,
                  float* __restrict__ cbbv)
{
  __shared__ float col[256];
  __shared__ float red[256];
  const int blk = blockIdx.x, tid = threadIdx.x;
  if (blk < 256) {
    const int e = blk;
    float cv = Wq[(size_t)tid * 256 + e];
    col[tid] = cv;
    red[tid] = bk[tid] * cv;
    __syncthreads();
    float a0 = 0.f, a1 = 0.f;
    for (int d = 0; d < 256; ++d) {
      float wq = col[d];
      a0 = fmaf(Wk[(size_t)d * 512 + tid], wq, a0);
      a1 = fmaf(Wk[(size_t)d * 512 + 256 + tid], wq, a1);
    }
    Bcomb[(size_t)(256 + e) * 512 + tid] = a0;
    Bcomb[(size_t)(256 + e) * 512 + 256 + tid] = a1;
    if (tid == 0) {
      float s = 0.f;
      for (int d = 0; d < 256; ++d) s += red[d];
      bias512[256 + e] = s;
    }
  } else {
    // misc block: Wv copy, bv, bsum, wkbq, cbb
    for (int i = tid; i < 256 * 512 / 4; i += 256)
      reinterpret_cast<float4*>(Bcomb)[i] = reinterpret_cast<const float4*>(Wv)[i];
    bias512[tid] = bv[tid];
    for (int i = tid; i < 1024; i += 256) bsum[i] = b_ih[i] + b_hh[i];
    float bqv = bq[tid];
    col[tid] = bqv;
    red[tid] = bk[tid] * bqv;
    __syncthreads();
    float a0 = 0.f, a1 = 0.f;
    for (int d = 0; d < 256; ++d) {
      float v = col[d];
      a0 = fmaf(Wk[(size_t)d * 512 + tid], v, a0);
      a1 = fmaf(Wk[(size_t)d * 512 + 256 + tid], v, a1);
    }
    wkbq[tid] = a0; wkbq[256 + tid] = a1;
    if (tid == 0) {
      float s = 0.f;
      for (int d = 0; d < 256; ++d) s += red[d];
      cbbv[0] = s;
    }
  }
}

// sb[r] = features[r,:] . wkbq + cbb   (exact f32)
__global__ void sb2_kernel(const float* __restrict__ features,
                           const float* __restrict__ wkbq,
                           const float* __restrict__ cbbv,
                           float* __restrict__ sb)
{
  int row  = blockIdx.x * 4 + (threadIdx.x >> 6);
  int lane = threadIdx.x & 63;
  const float* fr = features + (size_t)row * 512;
  float acc = 0.f;
#pragma unroll
  for (int k = 0; k < 8; ++k) acc = fmaf(fr[k * 64 + lane], wkbq[k * 64 + lane], acc);
#pragma unroll
  for (int off = 1; off < 64; off <<= 1) acc += __shfl_xor(acc, off);
  if (lane == 0) sb[row] = acc + cbbv[0];
}

// f32 -> bf16 convert
__global__ void cvt_kernel(const float* __restrict__ src, ushort* __restrict__ dst, int n4)
{
  int i = blockIdx.x * 256 + threadIdx.x;
  if (i < n4) {
    float4 x = reinterpret_cast<const float4*>(src)[i];
    ushort4 h; h.x = f2bf(x.x); h.y = f2bf(x.y); h.z = f2bf(x.z); h.w = f2bf(x.w);
    reinterpret_cast<ushort4*>(dst)[i] = h;
  }
}

// ---------------------------------------------------------------------------
// Sequential scan, batch-decoupled: 16 independent groups of 8 blocks.
// Tagged 64-bit payloads (hi32 = t+1), parity double-buffered. Distributed
// combine polls (round-2 lesson: all-threads-poll-all regresses). 6 barriers:
// B3 removed — every wave redundantly computes all 128 ctx pairs from the
// part[] combine partials and re-reads them after an in-wave lgkmcnt(0)
// (same values from all waves -> benign LDS race).
// ---------------------------------------------------------------------------
struct ScanSmem2 {
  unsigned k2p[64][131];   // K2 slice, f16 pairs (stride 131: 2-way banks, free)
  unsigned vtp[256][35];   // V slice transposed [e][jp]
  unsigned xw[288];        // x = [ctx|h] f16 pairs, 4 chunks x 72
  unsigned psp[32];        // softmax p, f16 pairs
  float Erow[128];
  float gout[128];
  float ml[8][2];          // per-slice (m, l)
  float part[8][130];      // ctx combine partials [2q+comp][pair]
  float sc[8][64];         // score partials
  float sbs[64];
};

DEVI int xwi(int w) { return (w >> 6) * 72 + (w & 63); }

__global__ __launch_bounds__(512, 1)
void scan2_kernel(const float* __restrict__ E, const float* __restrict__ KV2,
                  const float* __restrict__ sbg,
                  const float* __restrict__ W_ih, const float* __restrict__ W_hh,
                  ushort* __restrict__ hcb16,
                  ull* __restrict__ Hx,    // [2][16][128]
                  ull* __restrict__ Px)    // [2][16][8][130]
{
  extern __shared__ char smraw[];
  ScanSmem2& sm = *reinterpret_cast<ScanSmem2*>(smraw);
  const int g = blockIdx.x, tid = threadIdx.x;
  const int b = g >> 3, ss = g & 7;

  // ---- persistent LDS init (KV2 row layout: [0:256]=vals, [256:512]=K2)
  for (int idx = tid; idx < 64 * 128; idx += 512) {
    int j = idx >> 7, i = idx & 127;
    const float* src = KV2 + (size_t)(b * 512 + ss * 64 + j) * 512 + 256 + 2 * i;
    sm.k2p[j][i] = packh2(src[0], src[1]);
  }
  for (int idx = tid; idx < 256 * 32; idx += 512) {
    int e = idx >> 5, jp = idx & 31;
    float v0 = KV2[(size_t)(b * 512 + ss * 64 + 2 * jp) * 512 + e];
    float v1 = KV2[(size_t)(b * 512 + ss * 64 + 2 * jp + 1) * 512 + e];
    sm.vtp[e][jp] = packh2(v0, v1);
  }
  if (tid < 64) sm.sbs[tid] = sbg[b * 512 + ss * 64 + tid];
  for (int i = tid; i < 288; i += 512) sm.xw[i] = 0;   // ctx0 = h0 = 0

  // ---- gate-weight slice -> registers (f16 pairs), 4 threads per gate row
  const int r  = tid >> 2, h4 = tid & 3;
  const int grow = (r >> 5) * 256 + ss * 32 + (r & 31);  // PyTorch i,f,g,o order
  const float* wsrc = (h4 < 2)
      ? (W_ih + (size_t)grow * 512 + 256 + h4 * 128)     // x[0:256] = ctx
      : (W_hh + (size_t)grow * 256 + (h4 - 2) * 128);    // x[256:512] = h
  unsigned wreg[64];
#pragma unroll
  for (int i = 0; i < 32; ++i) {
    float4 w4 = reinterpret_cast<const float4*>(wsrc)[i];
    wreg[2 * i]     = packh2(w4.x, w4.y);
    wreg[2 * i + 1] = packh2(w4.z, w4.w);
  }

  float c_reg = 0.f;          // cell state, tid<32 only
  __syncthreads();

  const size_t hxb = (size_t)b * 128;
  const size_t pxb = (size_t)b * (8 * 130);

  for (int t = 0; t <= 128; ++t) {
    // E prefetch for this step
    float epf = 0.f;
    if (t < 128 && tid < 128)
      epf = E[(size_t)(b * 128 + t) * 1024 + (tid >> 5) * 256 + ss * 32 + (tid & 31)];

    float accg = 0.f;
    if (t > 0) {
      const unsigned tag = (unsigned)t;
      const ull* PxP = Px + (size_t)((t - 1) & 1) * (16 * 8 * 130) + pxb;
      const int e2 = tid & 127, q = tid >> 7;
      const ull* p1 = &PxP[(2 * q) * 130 + e2];
      const ull* p2 = &PxP[(2 * q + 1) * 130 + e2];
      // issue poll loads first: 2 ctx words/thread + (tid<16) 1 m/l word
      ull w1 = gload64(p1), w2 = gload64(p2);
      const ull* pm = &PxP[(tid >> 1) * 130 + 128 + (tid & 1)];
      ull wm = (tid < 16) ? gload64(pm) : 0;

      // ---- Wh @ h(t-1) half of the gate matvec, under the RT window
      if (h4 >= 2) {
        const unsigned* xsrc = sm.xw + h4 * 72;
#pragma unroll
        for (int i = 0; i < 16; ++i) {
          uint4 xv = *reinterpret_cast<const uint4*>(xsrc + 4 * i);
          accg = dot2(wreg[4 * i + 0], xv.x, accg);
          accg = dot2(wreg[4 * i + 1], xv.y, accg);
          accg = dot2(wreg[4 * i + 2], xv.z, accg);
          accg = dot2(wreg[4 * i + 3], xv.w, accg);
        }
      }

      if (tid < 16) {
        while ((unsigned)(wm >> 32) != tag) { __builtin_amdgcn_s_sleep(1); wm = gload64(pm); }
        sm.ml[tid >> 1][tid & 1] = __uint_as_float((unsigned)wm);
      }
      while ((unsigned)(w1 >> 32) != tag) { __builtin_amdgcn_s_sleep(1); w1 = gload64(p1); }
      while ((unsigned)(w2 >> 32) != tag) { __builtin_amdgcn_s_sleep(1); w2 = gload64(p2); }
      __syncthreads();   // B1: sm.ml ready
      float M = sm.ml[0][0];
#pragma unroll
      for (int s3 = 1; s3 < 8; ++s3) M = fmaxf(M, sm.ml[s3][0]);
      float L = 0.f;
#pragma unroll
      for (int s3 = 0; s3 < 8; ++s3) L += sm.ml[s3][1] * __expf(sm.ml[s3][0] - M);
      float rcpL = 1.f / L;
      float wf0 = __expf(sm.ml[2 * q][0] - M);
      float wf1 = __expf(sm.ml[2 * q + 1][0] - M);
      f16x2 x1 = __builtin_bit_cast(f16x2, (unsigned)w1);
      f16x2 x2 = __builtin_bit_cast(f16x2, (unsigned)w2);
      // part[2q+comp][pair]
      float2 pw0; pw0.x = wf0 * (float)x1[0] + wf1 * (float)x2[0];
      float2 pw1; pw1.x = wf0 * (float)x1[1] + wf1 * (float)x2[1];
      sm.part[2 * q][e2]     = pw0.x;
      sm.part[2 * q + 1][e2] = pw1.x;
      __syncthreads();   // B2: part ready
      // ---- all-wave ctx recompute (replaces B3): lane l -> pairs 2l, 2l+1
      {
        const int l = tid & 63;
        float2 f0[8];
#pragma unroll
        for (int s4 = 0; s4 < 8; ++s4)
          f0[s4] = *reinterpret_cast<const float2*>(&sm.part[s4][2 * l]);
        float c00 = (f0[0].x + f0[2].x + f0[4].x + f0[6].x) * rcpL;
        float c01 = (f0[1].x + f0[3].x + f0[5].x + f0[7].x) * rcpL;
        float c10 = (f0[0].y + f0[2].y + f0[4].y + f0[6].y) * rcpL;
        float c11 = (f0[1].y + f0[3].y + f0[5].y + f0[7].y) * rcpL;
        sm.xw[xwi(2 * l)]     = packh2(c00, c01);
        sm.xw[xwi(2 * l + 1)] = packh2(c10, c11);
        if (tid < 64) {
          ushort4 st;
          st.x = f2bf(c00); st.y = f2bf(c01); st.z = f2bf(c10); st.w = f2bf(c11);
          *reinterpret_cast<ushort4*>(
              hcb16 + (size_t)(b * 128 + (t - 1)) * 512 + 256 + 4 * l) = st;
        }
      }
    }
    if (t == 128) break;
    if (tid < 128) sm.Erow[tid] = epf;

    // ---- ctx-half gates (h-half done under the RT; both zero at t==0).
    // In-wave ordering only: this wave wrote ALL ctx pairs above.
    if (t > 0) {
      asm volatile("s_waitcnt lgkmcnt(0)" ::: "memory");
      __builtin_amdgcn_sched_barrier(0);
      if (h4 < 2) {
        const unsigned* xsrc = sm.xw + h4 * 72;
#pragma unroll
        for (int i = 0; i < 16; ++i) {
          uint4 xv = *reinterpret_cast<const uint4*>(xsrc + 4 * i);
          accg = dot2(wreg[4 * i + 0], xv.x, accg);
          accg = dot2(wreg[4 * i + 1], xv.y, accg);
          accg = dot2(wreg[4 * i + 2], xv.z, accg);
          accg = dot2(wreg[4 * i + 3], xv.w, accg);
        }
      }
    }
    accg += __shfl_xor(accg, 1);
    accg += __shfl_xor(accg, 2);
    if (h4 == 0) sm.gout[r] = accg;
    __syncthreads();     // B4: gout + Erow ready

    // ---- LSTM pointwise + h publish (tagged)
    if (tid < 32) {
      float gi = sm.gout[tid]      + sm.Erow[tid];
      float gf = sm.gout[32 + tid] + sm.Erow[32 + tid];
      float gg = sm.gout[64 + tid] + sm.Erow[64 + tid];
      float go = sm.gout[96 + tid] + sm.Erow[96 + tid];
      float iv = sigmoidf_(gi), fv = sigmoidf_(gf), ov = sigmoidf_(go);
      float gv = tanh_fast(gg);
      c_reg = fv * c_reg + iv * gv;
      float hn = ov * tanh_fast(c_reg);
      hcb16[(size_t)(b * 128 + t) * 512 + ss * 32 + tid] = f2bf(hn);
      float ho = __shfl_xor(hn, 1);
      if (!(tid & 1)) {
        unsigned pk = packh2(hn, ho);
        int w = ss * 16 + (tid >> 1);
        sm.xw[xwi(128 + w)] = pk;
        gstore64(&Hx[(size_t)(t & 1) * 2048 + hxb + w],
                 ((ull)(unsigned)(t + 1) << 32) | pk);
      }
    }
    // ---- poll peers' h(t)
    if (tid < 128 && (tid >> 4) != ss) {
      const ull* hp = &Hx[(size_t)(t & 1) * 2048 + hxb + tid];
      ull w = gload64(hp);
      while ((unsigned)(w >> 32) != (unsigned)(t + 1)) {
        __builtin_amdgcn_s_sleep(1); w = gload64(hp);
      }
      sm.xw[xwi(128 + tid)] = (unsigned)w;
    }
    __syncthreads();     // B5: full h(t) in LDS

    // ---- scores: 64 keys x 256; lane = key row (stride-131 2-way, free)
    {
      const int j = tid & 63, qq = tid >> 6;
      float acc2 = 0.f;
#pragma unroll
      for (int i = 0; i < 16; ++i)
        acc2 = dot2(sm.k2p[j][qq * 16 + i], sm.xw[xwi(128 + qq * 16 + i)], acc2);
      sm.sc[qq][j] = acc2;
    }
    __syncthreads();     // B6: score partials ready
    if (tid < 64) {
      float s = sm.sc[0][tid] + sm.sc[1][tid] + sm.sc[2][tid] + sm.sc[3][tid]
              + sm.sc[4][tid] + sm.sc[5][tid] + sm.sc[6][tid] + sm.sc[7][tid]
              + sm.sbs[tid];
      float mx = s;
#pragma unroll
      for (int off = 1; off < 64; off <<= 1) mx = fmaxf(mx, __shfl_xor(mx, off));
      float p = __expf(s - mx);
      float ls = p;
#pragma unroll
      for (int off = 1; off < 64; off <<= 1) ls += __shfl_xor(ls, off);
      if (tid == 0) {
        ull tg = (ull)(unsigned)(t + 1) << 32;
        ull* PxS = Px + (size_t)(t & 1) * (16 * 8 * 130) + pxb + ss * 130;
        gstore64(&PxS[128], tg | __float_as_uint(mx));
        gstore64(&PxS[129], tg | __float_as_uint(ls));
      }
      float ph = __shfl_xor(p, 1);
      if (!(tid & 1)) sm.psp[tid >> 1] = packh2(p, ph);
    }
    __syncthreads();     // B7: psp ready
    // ---- PV: 1 thread per dim (psp broadcast, vtp stride-35 2-way free)
    if (tid < 256) {
      float acc2 = 0.f;
#pragma unroll
      for (int jp = 0; jp < 32; ++jp) acc2 = dot2(sm.psp[jp], sm.vtp[tid][jp], acc2);
      float ao = __shfl_xor(acc2, 1);
      if (!(tid & 1)) {
        ull* PxS = Px + (size_t)(t & 1) * (16 * 8 * 130) + pxb + ss * 130;
        gstore64(&PxS[tid >> 1], ((ull)(unsigned)(t + 1) << 32) | packh2(acc2, ao));
      }
    }
    // no barrier: next iteration's tagged polls provide the ordering
  }
}

// ---------------------------------------------------------------------------
extern "C" void kernel_launch(void* const* d_in, const int* in_sizes, int n_in,
                              void* d_out, int out_size, void* d_ws, size_t ws_size,
                              hipStream_t stream)
{
  const int*   inputs   = (const int*)  d_in[0];
  const float* features = (const float*)d_in[1];
  const float* emb      = (const float*)d_in[2];
  const float* W_ih     = (const float*)d_in[3];
  const float* W_hh     = (const float*)d_in[4];
  const float* b_ih     = (const float*)d_in[5];
  const float* b_hh     = (const float*)d_in[6];
  const float* Wq       = (const float*)d_in[7];
  const float* bq       = (const float*)d_in[8];
  const float* Wk       = (const float*)d_in[9];
  const float* bk       = (const float*)d_in[10];
  const float* Wv       = (const float*)d_in[11];
  const float* bv       = (const float*)d_in[12];
  const float* Wo       = (const float*)d_in[13];
  const float* bo       = (const float*)d_in[14];
  float* out = (float*)d_out;

  char* ws = (char*)d_ws;
  size_t off = 0;
  auto alloc = [&](size_t bytes) -> char* {
    char* p = ws + off;
    off += (bytes + 255) & ~size_t(255);
    return p;
  };
  float*  KV2   = (float*) alloc((size_t)8192 * 512 * 4);  // [vals | K2]
  float*  E     = (float*) alloc((size_t)2048 * 1024 * 4);
  float*  Bcomb = (float*) alloc((size_t)512 * 512 * 4);
  float*  bias512 = (float*)alloc((size_t)512 * 4);
  float*  sb    = (float*) alloc((size_t)8192 * 4);
  float*  bsum  = (float*) alloc((size_t)1024 * 4);
  float*  wkbq  = (float*) alloc((size_t)512 * 4);
  float*  cbbv  = (float*) alloc((size_t)64 * 4);
  ushort* hcb16 = (ushort*)alloc((size_t)2048 * 512 * 2);
  ull*    Hx    = (ull*)   alloc((size_t)2 * 16 * 128 * 8);
  ull*    Px    = (ull*)   alloc((size_t)2 * 16 * 8 * 130 * 8);

  // Wo in bf16 (32.8 MB) if workspace allows; numerically identical to the
  // per-tile f2bf the GEMM would otherwise do.
  const size_t woBytes = (size_t)32000 * 512 * 2;
  ushort* Wo16 = nullptr;
  if (off + woBytes + 256 <= ws_size) Wo16 = (ushort*)alloc(woBytes);

  hipMemsetAsync(Hx, 0, (size_t)2 * 16 * 128 * 8, stream);
  hipMemsetAsync(Px, 0, (size_t)2 * 16 * 8 * 130 * 8, stream);

  prep2_kernel<<<257, 256, 0, stream>>>(Wk, Wq, Wv, bk, bq, b_ih, b_hh, bv,
                                        Bcomb, bias512, bsum, wkbq, cbbv);

  // fused vals+K2 GEMM: full-GPU grid (256 blocks)
  gemm_kernel<true, false, false, false><<<dim3(64, 4), 256, 0, stream>>>(
      features, 512, nullptr, Bcomb, 512, bias512, KV2, 512, 512);
  sb2_kernel<<<2048, 256, 0, stream>>>(features, wkbq, cbbv, sb);
  gemm_kernel<true, false, false, false><<<dim3(16, 8), 256, 0, stream>>>(
      emb, 256, inputs, W_ih, 512, bsum, E, 1024, 256);

  if (Wo16) cvt_kernel<<<16000, 256, 0, stream>>>(Wo, Wo16, 32000 * 512 / 4);

  hipFuncSetAttribute(reinterpret_cast<const void*>(scan2_kernel),
                      hipFuncAttributeMaxDynamicSharedMemorySize, (int)sizeof(ScanSmem2));
  scan2_kernel<<<128, 512, sizeof(ScanSmem2), stream>>>(E, KV2, sb, W_ih, W_hh,
                                                        hcb16, Hx, Px);

  if (Wo16)
    gemm_kernel<false, true, true, true><<<4096, 256, 0, stream>>>(
        hcb16, 512, nullptr, Wo16, 512, bo, out, 32000, 512);
  else
    gemm_kernel<false, true, false, true><<<4096, 256, 0, stream>>>(
        hcb16, 512, nullptr, Wo, 512, bo, out, 32000, 512);
}

// Round 6
// 1246.053 us; speedup vs baseline: 1.1452x; 1.1452x over previous
//
#include <hip/hip_runtime.h>
#include <hip/hip_fp16.h>

#define DEVI __device__ __forceinline__

typedef __attribute__((ext_vector_type(4))) float f32x4;
typedef __attribute__((ext_vector_type(8))) short bf16x8;
typedef __attribute__((ext_vector_type(8))) _Float16 f16x8;
typedef __attribute__((ext_vector_type(2))) _Float16 f16x2;
typedef unsigned long long ull;

DEVI ushort f2bf(float x) {
  union { float f; unsigned u; } v; v.f = x;
  unsigned r = v.u + 0x7fffu + ((v.u >> 16) & 1u);
  return (ushort)(r >> 16);
}
DEVI float bf2f(ushort b) {
  union { unsigned u; float f; } v; v.u = ((unsigned)b) << 16; return v.f;
}
DEVI unsigned packh2(float a, float b) {
  return ((unsigned)__half_as_ushort(__float2half(b)) << 16) |
         (unsigned)__half_as_ushort(__float2half(a));
}
DEVI float dot2(unsigned a, unsigned b, float c) {
#if __has_builtin(__builtin_amdgcn_fdot2)
  return __builtin_amdgcn_fdot2(__builtin_bit_cast(f16x2, a),
                                __builtin_bit_cast(f16x2, b), c, false);
#else
  f16x2 ha = __builtin_bit_cast(f16x2, a), hb = __builtin_bit_cast(f16x2, b);
  return c + (float)ha[0] * (float)hb[0] + (float)ha[1] * (float)hb[1];
#endif
}
DEVI float sigmoidf_(float x) { return 1.f / (1.f + __expf(-x)); }
// NaN-free fast tanh: e=exp(2x); 1-2/(e+1). e=inf -> 1, e=0 -> -1.
DEVI float tanh_fast(float x) {
  float e = __expf(2.f * x);
  return 1.f - 2.f / (e + 1.f);
}

// relaxed agent-scope (L3 coherence point) 64-bit tagged-word accesses
DEVI void gstore64(ull* p, ull v) {
  __hip_atomic_store(p, v, __ATOMIC_RELAXED, __HIP_MEMORY_SCOPE_AGENT);
}
DEVI ull gload64(const ull* p) {
  return __hip_atomic_load(p, __ATOMIC_RELAXED, __HIP_MEMORY_SCOPE_AGENT);
}

// async global->LDS, 16B per lane: HW writes lane l's 16B at (uniform dst)+l*16
DEVI void gload_lds16(const ushort* g, ushort* l) {
  __builtin_amdgcn_global_load_lds(
      (const __attribute__((address_space(1))) void*)g,
      (__attribute__((address_space(3))) void*)l, 16, 0, 0);
}

// ---------------------------------------------------------------------------
// Generic 128x128-tile bf16 MFMA GEMM:  C[M,N] = A[M,K] @ Bw[N,K]^T + bias
// SPLIT=true: hi/lo split-bf16, 3 MFMA passes (~fp32 accuracy).
// ABF16/BBF16: operand already bf16 (ushort) in gmem.
// ---------------------------------------------------------------------------
template<bool SPLIT, bool ABF16, bool BBF16>
__global__ __launch_bounds__(256)
void gemm_kernel(const void* __restrict__ A_, int lda, const int* __restrict__ Aidx,
                 const void* __restrict__ Bw_, int ldb,
                 const float* __restrict__ bias, float* __restrict__ C,
                 int N, int K)
{
  constexpr int BK  = SPLIT ? 32 : 64;
  constexpr int LDT = BK + 8;
  constexpr int NV  = (128 * BK / 4) / 256;

  __shared__ ushort Ah[128 * LDT];
  __shared__ ushort Bh[128 * LDT];
  __shared__ ushort Al[SPLIT ? 128 * LDT : 4];
  __shared__ ushort Bl[SPLIT ? 128 * LDT : 4];

  const int tid  = threadIdx.x;
  const int bm   = blockIdx.x * 128, bn = blockIdx.y * 128;
  const int lane = tid & 63, wave = tid >> 6;
  const int wr   = wave >> 1, wc = wave & 1;
  const int fr   = lane & 15, quad = lane >> 4;

  f32x4 acc[4][4] = {};

  for (int kt = 0; kt < K; kt += BK) {
    __syncthreads();
#pragma unroll
    for (int i = 0; i < NV; ++i) {
      int v   = i * 256 + tid;
      int row = v / (BK / 4);
      int c4  = (v % (BK / 4)) * 4;
      int arow = Aidx ? Aidx[bm + row] : (bm + row);
      if (ABF16) {
        const ushort* A = (const ushort*)A_;
        ushort4 h = *reinterpret_cast<const ushort4*>(A + (size_t)arow * lda + kt + c4);
        *reinterpret_cast<ushort4*>(&Ah[row * LDT + c4]) = h;
      } else {
        const float* A = (const float*)A_;
        const float4 x = *reinterpret_cast<const float4*>(A + (size_t)arow * lda + kt + c4);
        ushort4 h; h.x = f2bf(x.x); h.y = f2bf(x.y); h.z = f2bf(x.z); h.w = f2bf(x.w);
        *reinterpret_cast<ushort4*>(&Ah[row * LDT + c4]) = h;
        if (SPLIT) {
          ushort4 l;
          l.x = f2bf(x.x - bf2f(h.x)); l.y = f2bf(x.y - bf2f(h.y));
          l.z = f2bf(x.z - bf2f(h.z)); l.w = f2bf(x.w - bf2f(h.w));
          *reinterpret_cast<ushort4*>(&Al[row * LDT + c4]) = l;
        }
      }
    }
#pragma unroll
    for (int i = 0; i < NV; ++i) {
      int v   = i * 256 + tid;
      int row = v / (BK / 4);
      int c4  = (v % (BK / 4)) * 4;
      if (BBF16) {
        const ushort* B16 = (const ushort*)Bw_;
        ushort4 h = *reinterpret_cast<const ushort4*>(B16 + (size_t)(bn + row) * ldb + kt + c4);
        *reinterpret_cast<ushort4*>(&Bh[row * LDT + c4]) = h;
      } else {
        const float* Bw = (const float*)Bw_;
        const float4 x = *reinterpret_cast<const float4*>(Bw + (size_t)(bn + row) * ldb + kt + c4);
        ushort4 h; h.x = f2bf(x.x); h.y = f2bf(x.y); h.z = f2bf(x.z); h.w = f2bf(x.w);
        *reinterpret_cast<ushort4*>(&Bh[row * LDT + c4]) = h;
        if (SPLIT) {
          ushort4 l;
          l.x = f2bf(x.x - bf2f(h.x)); l.y = f2bf(x.y - bf2f(h.y));
          l.z = f2bf(x.z - bf2f(h.z)); l.w = f2bf(x.w - bf2f(h.w));
          *reinterpret_cast<ushort4*>(&Bl[row * LDT + c4]) = l;
        }
      }
    }
    __syncthreads();
#pragma unroll
    for (int ks = 0; ks < BK; ks += 32) {
      bf16x8 ah[4], bh[4];
#pragma unroll
      for (int i = 0; i < 4; ++i) {
        ah[i] = *reinterpret_cast<const bf16x8*>(&Ah[(wr * 64 + i * 16 + fr) * LDT + ks + quad * 8]);
        bh[i] = *reinterpret_cast<const bf16x8*>(&Bh[(wc * 64 + i * 16 + fr) * LDT + ks + quad * 8]);
      }
      if (SPLIT) {
        bf16x8 al[4], bl[4];
#pragma unroll
        for (int i = 0; i < 4; ++i) {
          al[i] = *reinterpret_cast<const bf16x8*>(&Al[(wr * 64 + i * 16 + fr) * LDT + ks + quad * 8]);
          bl[i] = *reinterpret_cast<const bf16x8*>(&Bl[(wc * 64 + i * 16 + fr) * LDT + ks + quad * 8]);
        }
#pragma unroll
        for (int i = 0; i < 4; ++i)
#pragma unroll
          for (int j = 0; j < 4; ++j) {
            acc[i][j] = __builtin_amdgcn_mfma_f32_16x16x32_bf16(ah[i], bh[j], acc[i][j], 0, 0, 0);
            acc[i][j] = __builtin_amdgcn_mfma_f32_16x16x32_bf16(ah[i], bl[j], acc[i][j], 0, 0, 0);
            acc[i][j] = __builtin_amdgcn_mfma_f32_16x16x32_bf16(al[i], bh[j], acc[i][j], 0, 0, 0);
          }
      } else {
#pragma unroll
        for (int i = 0; i < 4; ++i)
#pragma unroll
          for (int j = 0; j < 4; ++j)
            acc[i][j] = __builtin_amdgcn_mfma_f32_16x16x32_bf16(ah[i], bh[j], acc[i][j], 0, 0, 0);
      }
    }
  }
#pragma unroll
  for (int i = 0; i < 4; ++i)
#pragma unroll
    for (int j = 0; j < 4; ++j)
#pragma unroll
      for (int r = 0; r < 4; ++r) {
        int m = bm + wr * 64 + i * 16 + quad * 4 + r;
        int n = bn + wc * 64 + j * 16 + fr;
        float vv = acc[i][j][r];
        if (bias) vv += bias[n];
        C[(size_t)m * N + n] = vv;
      }
}

// ---------------------------------------------------------------------------
// Dedicated out-GEMM, m97 structure: both operands bf16 in gmem, staged via
// global_load_lds width-16 into LINEAR [128][32] LDS tiles (gload_lds needs
// a linear wave-uniform dest; verified m97 layout). 1-D grid of 4096 blocks
// with XCD-affinity swizzle: all 16 M-blocks of one N-slice get bid==y (mod 8)
// -> same XCD L2 -> the 128KB Wo slice is fetched once, not 8x.
// C[2048,32000] = A[2048,512] @ B[32000,512]^T + bias.
// ---------------------------------------------------------------------------
__global__ __launch_bounds__(256)
void ogemm_kernel(const ushort* __restrict__ A, const ushort* __restrict__ B,
                  const float* __restrict__ bias, float* __restrict__ C,
                  int N, int K)
{
  __shared__ ushort Ah[128 * 32];
  __shared__ ushort Bh[128 * 32];

  // swizzle: bid = ((yhi*16)+x)*8 + r8, y = yhi*8 + r8
  const int bid = blockIdx.x;
  const int r8 = bid & 7, k2 = bid >> 3;
  const int bx = k2 & 15, yhi = k2 >> 4;
  const int by = yhi * 8 + r8;
  if (by >= 250) return;
  const int bm = bx * 128, bn = by * 128;

  const int tid  = threadIdx.x;
  const int lane = tid & 63, w = tid >> 6;
  const int wr   = w >> 1, wc = w & 1;
  const int fr   = lane & 15, quad = lane >> 4;

  // staging: lane l of wave w fills LDS bytes [w*1024 + l*16) per issue;
  // tile row-major [128][32] bf16 -> row = w*16 + l/4, col = (l&3)*8
  const int srow = w * 16 + (lane >> 2);
  const int scol = (lane & 3) * 8;
  const ushort* ga = A + (size_t)(bm + srow) * K + scol;
  const ushort* gb = B + (size_t)(bn + srow) * K + scol;
  ushort* da = Ah + w * 512;   // byte offset w*1024 (wave-uniform)
  ushort* db = Bh + w * 512;
  const size_t half = (size_t)64 * K;   // rows 64..127

  f32x4 acc[4][4] = {};

  for (int kt = 0; kt < K; kt += 32) {
    __syncthreads();                       // prev compute done reading LDS
    gload_lds16(ga + kt, da);
    gload_lds16(ga + kt + half, da + 2048);
    gload_lds16(gb + kt, db);
    gload_lds16(gb + kt + half, db + 2048);
    __syncthreads();                       // vmcnt(0) drain -> tiles visible

    bf16x8 ah[4], bh[4];
#pragma unroll
    for (int i = 0; i < 4; ++i) {
      ah[i] = *reinterpret_cast<const bf16x8*>(&Ah[(wr * 64 + i * 16 + fr) * 32 + quad * 8]);
      bh[i] = *reinterpret_cast<const bf16x8*>(&Bh[(wc * 64 + i * 16 + fr) * 32 + quad * 8]);
    }
#pragma unroll
    for (int i = 0; i < 4; ++i)
#pragma unroll
      for (int j = 0; j < 4; ++j)
        acc[i][j] = __builtin_amdgcn_mfma_f32_16x16x32_bf16(ah[i], bh[j], acc[i][j], 0, 0, 0);
  }

#pragma unroll
  for (int i = 0; i < 4; ++i)
#pragma unroll
    for (int j = 0; j < 4; ++j)
#pragma unroll
      for (int r = 0; r < 4; ++r) {
        int m = bm + wr * 64 + i * 16 + quad * 4 + r;
        int n = bn + wc * 64 + j * 16 + fr;
        C[(size_t)m * N + n] = acc[i][j][r] + bias[n];
      }
}

// ---------------------------------------------------------------------------
// prep2: algebraic pre-fold in exact f32.
//   Bcomb rows 0:256   = Wv                      (vals = features@Wv^T + bv)
//   Bcomb rows 256+e,f = Wkq[f,e] = sum_d Wk[d,f]*Wq[d,e]
//   bias512 = [bv | bkq],  bkq[e] = sum_d bk[d]*Wq[d,e]
//   wkbq[f] = sum_d Wk[d,f]*bq[d],  cbb = bk.bq  (sb = features.wkbq + cbb)
//   bsum = b_ih + b_hh
// ---------------------------------------------------------------------------
__global__ __launch_bounds__(256)
void prep2_kernel(const float* __restrict__ Wk, const float* __restrict__ Wq,
                  const float* __restrict__ Wv, const float* __restrict__ bk,
                  const float* __restrict__ bq, const float* __restrict__ b_ih,
                  const float* __restrict__ b_hh, const float* __restrict__ bv,
                  float* __restrict__ Bcomb, float* __restrict__ bias512,
                  float* __restrict__ bsum, float* __restrict__ wkbq,
                  float* __restrict__ cbbv)
{
  __shared__ float col[256];
  __shared__ float red[256];
  const int blk = blockIdx.x, tid = threadIdx.x;
  if (blk < 256) {
    const int e = blk;
    float cv = Wq[(size_t)tid * 256 + e];
    col[tid] = cv;
    red[tid] = bk[tid] * cv;
    __syncthreads();
    float a0 = 0.f, a1 = 0.f;
    for (int d = 0; d < 256; ++d) {
      float wq = col[d];
      a0 = fmaf(Wk[(size_t)d * 512 + tid], wq, a0);
      a1 = fmaf(Wk[(size_t)d * 512 + 256 + tid], wq, a1);
    }
    Bcomb[(size_t)(256 + e) * 512 + tid] = a0;
    Bcomb[(size_t)(256 + e) * 512 + 256 + tid] = a1;
    if (tid == 0) {
      float s = 0.f;
      for (int d = 0; d < 256; ++d) s += red[d];
      bias512[256 + e] = s;
    }
  } else {
    // misc block: Wv copy, bv, bsum, wkbq, cbb
    for (int i = tid; i < 256 * 512 / 4; i += 256)
      reinterpret_cast<float4*>(Bcomb)[i] = reinterpret_cast<const float4*>(Wv)[i];
    bias512[tid] = bv[tid];
    for (int i = tid; i < 1024; i += 256) bsum[i] = b_ih[i] + b_hh[i];
    float bqv = bq[tid];
    col[tid] = bqv;
    red[tid] = bk[tid] * bqv;
    __syncthreads();
    float a0 = 0.f, a1 = 0.f;
    for (int d = 0; d < 256; ++d) {
      float v = col[d];
      a0 = fmaf(Wk[(size_t)d * 512 + tid], v, a0);
      a1 = fmaf(Wk[(size_t)d * 512 + 256 + tid], v, a1);
    }
    wkbq[tid] = a0; wkbq[256 + tid] = a1;
    if (tid == 0) {
      float s = 0.f;
      for (int d = 0; d < 256; ++d) s += red[d];
      cbbv[0] = s;
    }
  }
}

// sb[r] = features[r,:] . wkbq + cbb   (exact f32)
__global__ void sb2_kernel(const float* __restrict__ features,
                           const float* __restrict__ wkbq,
                           const float* __restrict__ cbbv,
                           float* __restrict__ sb)
{
  int row  = blockIdx.x * 4 + (threadIdx.x >> 6);
  int lane = threadIdx.x & 63;
  const float* fr = features + (size_t)row * 512;
  float acc = 0.f;
#pragma unroll
  for (int k = 0; k < 8; ++k) acc = fmaf(fr[k * 64 + lane], wkbq[k * 64 + lane], acc);
#pragma unroll
  for (int off = 1; off < 64; off <<= 1) acc += __shfl_xor(acc, off);
  if (lane == 0) sb[row] = acc + cbbv[0];
}

// f32 -> bf16 convert
__global__ void cvt_kernel(const float* __restrict__ src, ushort* __restrict__ dst, int n4)
{
  int i = blockIdx.x * 256 + threadIdx.x;
  if (i < n4) {
    float4 x = reinterpret_cast<const float4*>(src)[i];
    ushort4 h; h.x = f2bf(x.x); h.y = f2bf(x.y); h.z = f2bf(x.z); h.w = f2bf(x.w);
    reinterpret_cast<ushort4*>(dst)[i] = h;
  }
}

// ---------------------------------------------------------------------------
// Sequential scan, batch-decoupled: 16 independent groups of 8 blocks.
// Round-3 verified structure (643us): tagged 64-bit payloads, distributed
// combine polls, 7 barriers, Wh@h gate half under the first RT window,
// stride-131/35 LDS (2-way banks, free).
// ---------------------------------------------------------------------------
struct ScanSmem2 {
  unsigned k2p[64][131];   // K2 slice, f16 pairs (stride 131: 2-way banks, free)
  unsigned vtp[256][35];   // V slice transposed [e][jp]
  unsigned xw[288];        // x = [ctx|h] f16 pairs, 4 chunks x 72
  unsigned psp[32];        // softmax p, f16 pairs
  float Erow[128];
  float gout[128];
  float ml[8][2];          // per-slice (m, l)
  float cpart[4][128][2];  // ctx combine partials
  float sc[8][64];         // score partials
  float sbs[64];
};

DEVI int xwi(int w) { return (w >> 6) * 72 + (w & 63); }

__global__ __launch_bounds__(512, 1)
void scan2_kernel(const float* __restrict__ E, const float* __restrict__ KV2,
                  const float* __restrict__ sbg,
                  const float* __restrict__ W_ih, const float* __restrict__ W_hh,
                  ushort* __restrict__ hcb16,
                  ull* __restrict__ Hx,    // [2][16][128]
                  ull* __restrict__ Px)    // [2][16][8][130]
{
  extern __shared__ char smraw[];
  ScanSmem2& sm = *reinterpret_cast<ScanSmem2*>(smraw);
  const int g = blockIdx.x, tid = threadIdx.x;
  const int b = g >> 3, ss = g & 7;

  // ---- persistent LDS init (KV2 row layout: [0:256]=vals, [256:512]=K2)
  for (int idx = tid; idx < 64 * 128; idx += 512) {
    int j = idx >> 7, i = idx & 127;
    const float* src = KV2 + (size_t)(b * 512 + ss * 64 + j) * 512 + 256 + 2 * i;
    sm.k2p[j][i] = packh2(src[0], src[1]);
  }
  for (int idx = tid; idx < 256 * 32; idx += 512) {
    int e = idx >> 5, jp = idx & 31;
    float v0 = KV2[(size_t)(b * 512 + ss * 64 + 2 * jp) * 512 + e];
    float v1 = KV2[(size_t)(b * 512 + ss * 64 + 2 * jp + 1) * 512 + e];
    sm.vtp[e][jp] = packh2(v0, v1);
  }
  if (tid < 64) sm.sbs[tid] = sbg[b * 512 + ss * 64 + tid];
  for (int i = tid; i < 288; i += 512) sm.xw[i] = 0;   // ctx0 = h0 = 0

  // ---- gate-weight slice -> registers (f16 pairs), 4 threads per gate row
  const int r  = tid >> 2, h4 = tid & 3;
  const int grow = (r >> 5) * 256 + ss * 32 + (r & 31);  // PyTorch i,f,g,o order
  const float* wsrc = (h4 < 2)
      ? (W_ih + (size_t)grow * 512 + 256 + h4 * 128)     // x[0:256] = ctx
      : (W_hh + (size_t)grow * 256 + (h4 - 2) * 128);    // x[256:512] = h
  unsigned wreg[64];
#pragma unroll
  for (int i = 0; i < 32; ++i) {
    float4 w4 = reinterpret_cast<const float4*>(wsrc)[i];
    wreg[2 * i]     = packh2(w4.x, w4.y);
    wreg[2 * i + 1] = packh2(w4.z, w4.w);
  }

  float c_reg = 0.f;          // cell state, tid<32 only
  __syncthreads();

  const size_t hxb = (size_t)b * 128;
  const size_t pxb = (size_t)b * (8 * 130);

  for (int t = 0; t <= 128; ++t) {
    // E prefetch for this step
    float epf = 0.f;
    if (t < 128 && tid < 128)
      epf = E[(size_t)(b * 128 + t) * 1024 + (tid >> 5) * 256 + ss * 32 + (tid & 31)];

    float accg = 0.f;
    if (t > 0) {
      const unsigned tag = (unsigned)t;
      const ull* PxP = Px + (size_t)((t - 1) & 1) * (16 * 8 * 130) + pxb;
      const int e2 = tid & 127, q = tid >> 7;
      const ull* p1 = &PxP[(2 * q) * 130 + e2];
      const ull* p2 = &PxP[(2 * q + 1) * 130 + e2];
      // issue poll loads first: 2 ctx words/thread + (tid<16) 1 m/l word
      ull w1 = gload64(p1), w2 = gload64(p2);
      const ull* pm = &PxP[(tid >> 1) * 130 + 128 + (tid & 1)];
      ull wm = (tid < 16) ? gload64(pm) : 0;

      // ---- Wh @ h(t-1) half of the gate matvec, under the RT window
      if (h4 >= 2) {
        const unsigned* xsrc = sm.xw + h4 * 72;
#pragma unroll
        for (int i = 0; i < 16; ++i) {
          uint4 xv = *reinterpret_cast<const uint4*>(xsrc + 4 * i);
          accg = dot2(wreg[4 * i + 0], xv.x, accg);
          accg = dot2(wreg[4 * i + 1], xv.y, accg);
          accg = dot2(wreg[4 * i + 2], xv.z, accg);
          accg = dot2(wreg[4 * i + 3], xv.w, accg);
        }
      }

      if (tid < 16) {
        while ((unsigned)(wm >> 32) != tag) { __builtin_amdgcn_s_sleep(1); wm = gload64(pm); }
        sm.ml[tid >> 1][tid & 1] = __uint_as_float((unsigned)wm);
      }
      while ((unsigned)(w1 >> 32) != tag) { __builtin_amdgcn_s_sleep(1); w1 = gload64(p1); }
      while ((unsigned)(w2 >> 32) != tag) { __builtin_amdgcn_s_sleep(1); w2 = gload64(p2); }
      __syncthreads();   // B1: sm.ml ready
      float M = sm.ml[0][0];
#pragma unroll
      for (int s3 = 1; s3 < 8; ++s3) M = fmaxf(M, sm.ml[s3][0]);
      float L = 0.f;
#pragma unroll
      for (int s3 = 0; s3 < 8; ++s3) L += sm.ml[s3][1] * __expf(sm.ml[s3][0] - M);
      float rcpL = 1.f / L;
      float wf0 = __expf(sm.ml[2 * q][0] - M);
      float wf1 = __expf(sm.ml[2 * q + 1][0] - M);
      f16x2 x1 = __builtin_bit_cast(f16x2, (unsigned)w1);
      f16x2 x2 = __builtin_bit_cast(f16x2, (unsigned)w2);
      sm.cpart[q][e2][0] = wf0 * (float)x1[0] + wf1 * (float)x2[0];
      sm.cpart[q][e2][1] = wf0 * (float)x1[1] + wf1 * (float)x2[1];
      __syncthreads();   // B2: cpart ready
      if (tid < 128) {
        float c0 = (sm.cpart[0][tid][0] + sm.cpart[1][tid][0]
                  + sm.cpart[2][tid][0] + sm.cpart[3][tid][0]) * rcpL;
        float c1 = (sm.cpart[0][tid][1] + sm.cpart[1][tid][1]
                  + sm.cpart[2][tid][1] + sm.cpart[3][tid][1]) * rcpL;
        sm.xw[xwi(tid)] = packh2(c0, c1);
        ushort* dst = hcb16 + (size_t)(b * 128 + (t - 1)) * 512 + 256 + 2 * tid;
        dst[0] = f2bf(c0); dst[1] = f2bf(c1);
      }
    }
    if (t == 128) break;
    if (tid < 128) sm.Erow[tid] = epf;
    __syncthreads();     // B3: xw-ctx + Erow ready

    // ---- ctx-half gates (h-half done under the RT; both zero at t==0)
    if (t > 0 && h4 < 2) {
      const unsigned* xsrc = sm.xw + h4 * 72;
#pragma unroll
      for (int i = 0; i < 16; ++i) {
        uint4 xv = *reinterpret_cast<const uint4*>(xsrc + 4 * i);
        accg = dot2(wreg[4 * i + 0], xv.x, accg);
        accg = dot2(wreg[4 * i + 1], xv.y, accg);
        accg = dot2(wreg[4 * i + 2], xv.z, accg);
        accg = dot2(wreg[4 * i + 3], xv.w, accg);
      }
    }
    accg += __shfl_xor(accg, 1);
    accg += __shfl_xor(accg, 2);
    if (h4 == 0) sm.gout[r] = accg;
    __syncthreads();     // B4: gout ready

    // ---- LSTM pointwise + h publish (tagged)
    if (tid < 32) {
      float gi = sm.gout[tid]      + sm.Erow[tid];
      float gf = sm.gout[32 + tid] + sm.Erow[32 + tid];
      float gg = sm.gout[64 + tid] + sm.Erow[64 + tid];
      float go = sm.gout[96 + tid] + sm.Erow[96 + tid];
      float iv = sigmoidf_(gi), fv = sigmoidf_(gf), ov = sigmoidf_(go);
      float gv = tanh_fast(gg);
      c_reg = fv * c_reg + iv * gv;
      float hn = ov * tanh_fast(c_reg);
      hcb16[(size_t)(b * 128 + t) * 512 + ss * 32 + tid] = f2bf(hn);
      float ho = __shfl_xor(hn, 1);
      if (!(tid & 1)) {
        unsigned pk = packh2(hn, ho);
        int w = ss * 16 + (tid >> 1);
        sm.xw[xwi(128 + w)] = pk;
        gstore64(&Hx[(size_t)(t & 1) * 2048 + hxb + w],
                 ((ull)(unsigned)(t + 1) << 32) | pk);
      }
    }
    // ---- poll peers' h(t)
    if (tid < 128 && (tid >> 4) != ss) {
      const ull* hp = &Hx[(size_t)(t & 1) * 2048 + hxb + tid];
      ull w = gload64(hp);
      while ((unsigned)(w >> 32) != (unsigned)(t + 1)) {
        __builtin_amdgcn_s_sleep(1); w = gload64(hp);
      }
      sm.xw[xwi(128 + tid)] = (unsigned)w;
    }
    __syncthreads();     // B5: full h(t) in LDS

    // ---- scores: 64 keys x 256; lane = key row (stride-131 2-way, free)
    {
      const int j = tid & 63, qq = tid >> 6;
      float acc2 = 0.f;
#pragma unroll
      for (int i = 0; i < 16; ++i)
        acc2 = dot2(sm.k2p[j][qq * 16 + i], sm.xw[xwi(128 + qq * 16 + i)], acc2);
      sm.sc[qq][j] = acc2;
    }
    __syncthreads();     // B6: score partials ready
    if (tid < 64) {
      float s = sm.sc[0][tid] + sm.sc[1][tid] + sm.sc[2][tid] + sm.sc[3][tid]
              + sm.sc[4][tid] + sm.sc[5][tid] + sm.sc[6][tid] + sm.sc[7][tid]
              + sm.sbs[tid];
      float mx = s;
#pragma unroll
      for (int off = 1; off < 64; off <<= 1) mx = fmaxf(mx, __shfl_xor(mx, off));
      float p = __expf(s - mx);
      float ls = p;
#pragma unroll
      for (int off = 1; off < 64; off <<= 1) ls += __shfl_xor(ls, off);
      if (tid == 0) {
        ull tg = (ull)(unsigned)(t + 1) << 32;
        ull* PxS = Px + (size_t)(t & 1) * (16 * 8 * 130) + pxb + ss * 130;
        gstore64(&PxS[128], tg | __float_as_uint(mx));
        gstore64(&PxS[129], tg | __float_as_uint(ls));
      }
      float ph = __shfl_xor(p, 1);
      if (!(tid & 1)) sm.psp[tid >> 1] = packh2(p, ph);
    }
    __syncthreads();     // B7: psp ready
    // ---- PV: 1 thread per dim (psp broadcast, vtp stride-35 2-way free)
    if (tid < 256) {
      float acc2 = 0.f;
#pragma unroll
      for (int jp = 0; jp < 32; ++jp) acc2 = dot2(sm.psp[jp], sm.vtp[tid][jp], acc2);
      float ao = __shfl_xor(acc2, 1);
      if (!(tid & 1)) {
        ull* PxS = Px + (size_t)(t & 1) * (16 * 8 * 130) + pxb + ss * 130;
        gstore64(&PxS[tid >> 1], ((ull)(unsigned)(t + 1) << 32) | packh2(acc2, ao));
      }
    }
    // no barrier: next iteration's tagged polls provide the ordering
  }
}

// ---------------------------------------------------------------------------
extern "C" void kernel_launch(void* const* d_in, const int* in_sizes, int n_in,
                              void* d_out, int out_size, void* d_ws, size_t ws_size,
                              hipStream_t stream)
{
  const int*   inputs   = (const int*)  d_in[0];
  const float* features = (const float*)d_in[1];
  const float* emb      = (const float*)d_in[2];
  const float* W_ih     = (const float*)d_in[3];
  const float* W_hh     = (const float*)d_in[4];
  const float* b_ih     = (const float*)d_in[5];
  const float* b_hh     = (const float*)d_in[6];
  const float* Wq       = (const float*)d_in[7];
  const float* bq       = (const float*)d_in[8];
  const float* Wk       = (const float*)d_in[9];
  const float* bk       = (const float*)d_in[10];
  const float* Wv       = (const float*)d_in[11];
  const float* bv       = (const float*)d_in[12];
  const float* Wo       = (const float*)d_in[13];
  const float* bo       = (const float*)d_in[14];
  float* out = (float*)d_out;

  char* ws = (char*)d_ws;
  size_t off = 0;
  auto alloc = [&](size_t bytes) -> char* {
    char* p = ws + off;
    off += (bytes + 255) & ~size_t(255);
    return p;
  };
  float*  KV2   = (float*) alloc((size_t)8192 * 512 * 4);  // [vals | K2]
  float*  E     = (float*) alloc((size_t)2048 * 1024 * 4);
  float*  Bcomb = (float*) alloc((size_t)512 * 512 * 4);
  float*  bias512 = (float*)alloc((size_t)512 * 4);
  float*  sb    = (float*) alloc((size_t)8192 * 4);
  float*  bsum  = (float*) alloc((size_t)1024 * 4);
  float*  wkbq  = (float*) alloc((size_t)512 * 4);
  float*  cbbv  = (float*) alloc((size_t)64 * 4);
  ushort* hcb16 = (ushort*)alloc((size_t)2048 * 512 * 2);
  ull*    Hx    = (ull*)   alloc((size_t)2 * 16 * 128 * 8);
  ull*    Px    = (ull*)   alloc((size_t)2 * 16 * 8 * 130 * 8);

  // Wo in bf16 (32.8 MB) if workspace allows; numerically identical to the
  // per-tile f2bf the GEMM would otherwise do.
  const size_t woBytes = (size_t)32000 * 512 * 2;
  ushort* Wo16 = nullptr;
  if (off + woBytes + 256 <= ws_size) Wo16 = (ushort*)alloc(woBytes);

  hipMemsetAsync(Hx, 0, (size_t)2 * 16 * 128 * 8, stream);
  hipMemsetAsync(Px, 0, (size_t)2 * 16 * 8 * 130 * 8, stream);

  prep2_kernel<<<257, 256, 0, stream>>>(Wk, Wq, Wv, bk, bq, b_ih, b_hh, bv,
                                        Bcomb, bias512, bsum, wkbq, cbbv);

  // fused vals+K2 GEMM: full-GPU grid (256 blocks)
  gemm_kernel<true, false, false><<<dim3(64, 4), 256, 0, stream>>>(
      features, 512, nullptr, Bcomb, 512, bias512, KV2, 512, 512);
  sb2_kernel<<<2048, 256, 0, stream>>>(features, wkbq, cbbv, sb);
  gemm_kernel<true, false, false><<<dim3(16, 8), 256, 0, stream>>>(
      emb, 256, inputs, W_ih, 512, bsum, E, 1024, 256);

  if (Wo16) cvt_kernel<<<16000, 256, 0, stream>>>(Wo, Wo16, 32000 * 512 / 4);

  hipFuncSetAttribute(reinterpret_cast<const void*>(scan2_kernel),
                      hipFuncAttributeMaxDynamicSharedMemorySize, (int)sizeof(ScanSmem2));
  scan2_kernel<<<128, 512, sizeof(ScanSmem2), stream>>>(E, KV2, sb, W_ih, W_hh,
                                                        hcb16, Hx, Px);

  if (Wo16)
    ogemm_kernel<<<4096, 256, 0, stream>>>(hcb16, Wo16, bo, out, 32000, 512);
  else
    gemm_kernel<false, true, false><<<dim3(16, 250), 256, 0, stream>>>(
        hcb16, 512, nullptr, Wo, 512, bo, out, 32000, 512);
}